// Round 8
// baseline (182.669 us; speedup 1.0000x reference)
//
#include <hip/hip_runtime.h>
#include <stdint.h>

// Workspace byte offsets
#define OFF_W1  0        // 1024*32 u32 packed sign bits, channel-major (fallback)
#define OFF_W2  131072
#define OFF_W3  262144
#define OFF_WFC 393216   // 10*32 u32 (fallback FC)
#define OFF_T1  395264   // 1024 int32 popcount thresholds (fallback)
#define OFF_T2  399360
#define OFF_T3  403456
#define OFF_SFC 407552   // double: mean|wfc|
// v8 (MFMA): fragment-ordered i8 weight files. Layout per layer:
//   frag[(nt*16 + kt)*1024 + lane*16 + e], nt=ch>>4 (64), kt=k>>6 (16),
//   lane = (ch&15) | (((k>>4)&3)<<4), e = k&15.  1 MB per layer.
#define OFF_F1  409600
#define OFF_F2  1458176
#define OFF_F3  2506752
#define OFF_FFC 3555328  // 16 KB: wfc frags (16 cols: 10 real + 6 garbage-don't-care)
#define OFF_C1  3571712  // 1024 int32 dot-form thresholds (act = dot >= Cdot)
#define OFF_C2  3575808
#define OFF_C3  3579904
#define WS_NEED_V8 3584000u
#define RWS 16           // rows per block in fallback fused kernel

typedef int int4v __attribute__((ext_vector_type(4)));

// ---------------------------------------------------------------------------
// Prep — one dispatch: W bitpack (fallback) + i8 MFMA frags + thresholds
// (both popcount-form Td and dot-form Cdot) + wfc (both forms). 385 blocks.
// ---------------------------------------------------------------------------
__global__ __launch_bounds__(256) void bnn_prep(
    const float* __restrict__ w1, const float* __restrict__ b1, const float* __restrict__ g1,
    const float* __restrict__ be1, const float* __restrict__ m1, const float* __restrict__ v1,
    const float* __restrict__ w2, const float* __restrict__ b2, const float* __restrict__ g2,
    const float* __restrict__ be2, const float* __restrict__ m2, const float* __restrict__ v2,
    const float* __restrict__ w3, const float* __restrict__ b3, const float* __restrict__ g3,
    const float* __restrict__ be3, const float* __restrict__ m3, const float* __restrict__ v3,
    const float* __restrict__ wfc,
    uint32_t* __restrict__ ws)
{
    const int blk  = blockIdx.x;
    const int t    = threadIdx.x;
    const int lane = t & 63;
    const int wv   = t >> 6;

    if (blk < 384) {
        const int gid = blk * 256 + t;      // 0..98303
        const int l   = gid >> 15;          // layer 0..2 (32768 words each)
        const int rem = gid & 32767;
        const int o   = rem >> 5;           // channel
        const int k32 = rem & 31;           // word within channel
        const float *w, *bb, *g, *be, *m, *v;
        int K; uint32_t *Wp, *Fl; int *T, *Cdl;
        if (l == 0)      { w=w1; bb=b1; g=g1; be=be1; m=m1; v=v1; K=784;
                           Wp = ws + OFF_W1/4; Fl = ws + OFF_F1/4;
                           T = (int*)(ws + OFF_T1/4); Cdl = (int*)(ws + OFF_C1/4); }
        else if (l == 1) { w=w2; bb=b2; g=g2; be=be2; m=m2; v=v2; K=1024;
                           Wp = ws + OFF_W2/4; Fl = ws + OFF_F2/4;
                           T = (int*)(ws + OFF_T2/4); Cdl = (int*)(ws + OFF_C2/4); }
        else             { w=w3; bb=b3; g=g3; be=be3; m=m3; v=v3; K=1024;
                           Wp = ws + OFF_W3/4; Fl = ws + OFF_F3/4;
                           T = (int*)(ws + OFF_T3/4); Cdl = (int*)(ws + OFF_C3/4); }

        const int base = 32 * k32;
        uint32_t bits = 0;
        double s = 0.0;
        if (base < K) {
            const float4* p = (const float4*)(w + (size_t)o * K + base);
            const int n4 = (K - base >= 32) ? 8 : 4;   // K=784, k32=24 -> 16 elems
            for (int i = 0; i < n4; ++i) {
                float4 q = p[i];
                bits |= (q.x >= 0.0f) ? (1u << (4*i + 0)) : 0u;
                bits |= (q.y >= 0.0f) ? (1u << (4*i + 1)) : 0u;
                bits |= (q.z >= 0.0f) ? (1u << (4*i + 2)) : 0u;
                bits |= (q.w >= 0.0f) ? (1u << (4*i + 3)) : 0u;
                s += fabs((double)q.x) + fabs((double)q.y)
                   + fabs((double)q.z) + fabs((double)q.w);
            }
        }
        // half-wave (32-lane) xor tree: all lanes of the half get channel sum
        #pragma unroll
        for (int mask = 1; mask <= 16; mask <<= 1)
            s += __shfl_xor(s, mask, 64);
        if (k32 == 0) {
            double scale = s / (double)K;                        // mean|w| > 0
            double r = (double)g[o] / sqrt((double)v[o] + 1e-5); // > 0
            double tt = (((double)m[o] - (double)bb[o]) * r - (double)be[o]) / (scale * r);
            double C  = ceil(tt);                                // act=+1 iff dot >= C
            // dot-form threshold (MFMA path)
            double Cc = fmax(fmin(C, 100000.0), -100000.0);
            Cdl[o] = (int)Cc;
            // popcount-form (fallback path): p <= Td
            double Td = floor(((double)K - C) * 0.5);
            Td = fmax(fmin(Td, 100000.0), -1.0);
            T[o] = (int)Td;
        }
        Wp[(size_t)o * 32 + k32] = bits;                          // bitpacked

        // i8 fragment bytes: 32 bits -> two 16-byte groups in frag order.
        const int nt = o >> 4;
        #pragma unroll
        for (int g2i = 0; g2i < 2; ++g2i) {
            const int kg = base + g2i * 16;
            const int kt = kg >> 6;
            const int lane16 = (o & 15) | (((kg >> 4) & 3) << 4);
            uint32_t fb[4];
            #pragma unroll
            for (int wd = 0; wd < 4; ++wd) {
                uint32_t vv = 0;
                #pragma unroll
                for (int bj = 0; bj < 4; ++bj) {
                    const int idx = g2i*16 + wd*4 + bj;
                    const int kk  = base + idx;
                    uint32_t byte = (kk < K) ? (((bits >> idx) & 1u) ? 0x01u : 0xFFu) : 0x00u;
                    vv |= byte << (8*bj);
                }
                fb[wd] = vv;
            }
            uint32_t* dst = Fl + (size_t)((nt*16 + kt) * 256 + lane16 * 4);
            *(uint4*)dst = *(uint4*)fb;
        }
    } else {
        // wfc: 320 words (10 ch x 32); thread t does word t and (t<64) t+256
        uint32_t* Wp  = ws + OFF_WFC/4;
        uint32_t* Ffc = ws + OFF_FFC/4;
        double s = 0.0;
        #pragma unroll
        for (int part = 0; part < 2; ++part) {
            const int tt_ = t + part * 256;
            if (part == 1 && t >= 64) break;
            const int o = tt_ >> 5, k32 = tt_ & 31;
            const int base = 32 * k32;
            const float4* p = (const float4*)(wfc + o * 1024 + base);
            uint32_t bits = 0;
            #pragma unroll
            for (int i = 0; i < 8; ++i) {
                float4 q = p[i];
                bits |= (q.x >= 0.0f) ? (1u << (4*i + 0)) : 0u;
                bits |= (q.y >= 0.0f) ? (1u << (4*i + 1)) : 0u;
                bits |= (q.z >= 0.0f) ? (1u << (4*i + 2)) : 0u;
                bits |= (q.w >= 0.0f) ? (1u << (4*i + 3)) : 0u;
                s += fabs((double)q.x) + fabs((double)q.y)
                   + fabs((double)q.z) + fabs((double)q.w);
            }
            Wp[tt_] = bits;
            // frag bytes (nt=0; cols 10..15 left as don't-care)
            #pragma unroll
            for (int g2i = 0; g2i < 2; ++g2i) {
                const int kg = base + g2i * 16;
                const int kt = kg >> 6;
                const int lane16 = (o & 15) | (((kg >> 4) & 3) << 4);
                uint32_t fb[4];
                #pragma unroll
                for (int wd = 0; wd < 4; ++wd) {
                    uint32_t vv = 0;
                    #pragma unroll
                    for (int bj = 0; bj < 4; ++bj) {
                        const int idx = g2i*16 + wd*4 + bj;
                        vv |= (((bits >> idx) & 1u) ? 0x01u : 0xFFu) << (8*bj);
                    }
                    fb[wd] = vv;
                }
                *(uint4*)(Ffc + (size_t)(kt * 256 + lane16 * 4)) = *(uint4*)fb;
            }
        }
        __shared__ double red[4];
        #pragma unroll
        for (int off = 32; off > 0; off >>= 1) s += __shfl_down(s, off, 64);
        if (lane == 0) red[wv] = s;
        __syncthreads();
        if (t == 0)
            *(double*)(ws + OFF_SFC/4) = (red[0] + red[1] + red[2] + red[3]) / 10240.0;
    }
}

// ---------------------------------------------------------------------------
// v8 (R17): fused MFMA network. Block = 32 rows through all layers.
// i8 dot is exact: act in {+1,-1,0(pad)}, w in {+1,-1}; layer = dot >= Cdot.
// Acts as i8 in LDS (two 32KB buffers, byte XOR-swizzle ^((row&7)<<4) kills
// the stride-1024 bank hazard). Weights streamed as fragment-ordered i8 from
// L2 (B-frag = 1 coalesced dwordx4/lane). 16 waves: wave = 4 n-tiles x 2
// m-tiles; K-loop 16x v_mfma_i32_16x16x64_i8 (inline asm; s_nop hazards:
// 1 after acc init, 7x3 before acc reads). Assumed frag mapping (canonical
// CDNA blocked): A row=lane&15, k=(lane>>4)*16+e; B col=lane&15, same k;
// C/D col=lane&15, row=(lane>>4)*4+reg [guide: shape-determined, verified].
// ---------------------------------------------------------------------------
#define MFMA_I8(ACC, A, B) \
    asm volatile("v_mfma_i32_16x16x64_i8 %0, %1, %2, %0" \
                 : "+v"(ACC) : "v"(A), "v"(B))

__global__ __launch_bounds__(1024) void bnn_mfma(
    const float* __restrict__ x,
    uint32_t* __restrict__ ws,
    const float* __restrict__ bfc,
    float* __restrict__ out)
{
    __shared__ uint8_t actA[32 * 1024];
    __shared__ uint8_t actB[32 * 1024];
    const int t    = threadIdx.x;
    const int lane = t & 63;
    const int wv   = t >> 6;            // 0..15
    const int row0 = blockIdx.x * 32;

    // ---- stage layer-1 A: i8 sign(2x-1), zero-pad k in [784,1024) ----
    if (t < 256) {
        const int k4 = t * 4;
        #pragma unroll 4
        for (int i = 0; i < 32; ++i) {
            uint32_t wval = 0;
            if (k4 < 784) {   // k4 <= 780 -> all 4 elems < 784
                const float4 q = *(const float4*)(x + (size_t)(row0 + i) * 784 + k4);
                wval  = ((q.x >= 0.5f) ? 0x01u : 0xFFu);
                wval |= ((q.y >= 0.5f) ? 0x01u : 0xFFu) << 8;
                wval |= ((q.z >= 0.5f) ? 0x01u : 0xFFu) << 16;
                wval |= ((q.w >= 0.5f) ? 0x01u : 0xFFu) << 24;
            }
            *(uint32_t*)(actA + i * 1024 + (k4 ^ ((i & 7) << 4))) = wval;
        }
    }
    __syncthreads();

    const uint8_t* Wf[3] = { (const uint8_t*)ws + OFF_F1,
                             (const uint8_t*)ws + OFF_F2,
                             (const uint8_t*)ws + OFF_F3 };
    const int* Cd[3] = { (const int*)(ws + OFF_C1/4),
                         (const int*)(ws + OFF_C2/4),
                         (const int*)(ws + OFF_C3/4) };

    uint8_t* cur = actA;
    uint8_t* nxt = actB;
    const int nq  = wv * 4;        // first of this wave's 4 n-tiles
    const int col = lane & 15;
    const int lg  = lane >> 4;     // 0..3

    #pragma unroll 1
    for (int l = 0; l < 3; ++l) {
        int4v acc[2][4];
        #pragma unroll
        for (int m = 0; m < 2; ++m)
            #pragma unroll
            for (int n = 0; n < 4; ++n)
                acc[m][n] = (int4v){0, 0, 0, 0};
        asm volatile("s_nop 1" ::: );     // VALU write -> MFMA srcC wait states

        const uint8_t* Wl = Wf[l];
        const int ra = col, rb = 16 + col;
        #pragma unroll 2
        for (int kt = 0; kt < 16; ++kt) {
            const int k0 = kt * 64 + lg * 16;
            int4v a0 = *(const int4v*)(cur + ra * 1024 + (k0 ^ ((ra & 7) << 4)));
            int4v a1 = *(const int4v*)(cur + rb * 1024 + (k0 ^ ((rb & 7) << 4)));
            #pragma unroll
            for (int nt = 0; nt < 4; ++nt) {
                int4v b = *(const int4v*)(Wl + ((size_t)((nq + nt) * 16 + kt) << 10) + lane * 16);
                MFMA_I8(acc[0][nt], a0, b);
                MFMA_I8(acc[1][nt], a1, b);
            }
        }
        asm volatile("s_nop 7\n\ts_nop 7\n\ts_nop 7" ::: );   // MFMA -> VALU read

        const int* Cdl = Cd[l];
        #pragma unroll
        for (int nt = 0; nt < 4; ++nt) {
            const int ch  = (nq + nt) * 16 + col;
            const int thr = Cdl[ch];
            #pragma unroll
            for (int m = 0; m < 2; ++m) {
                #pragma unroll
                for (int reg = 0; reg < 4; ++reg) {
                    const int rr = m * 16 + lg * 4 + reg;
                    nxt[rr * 1024 + (ch ^ ((rr & 7) << 4))] =
                        (acc[m][nt][reg] >= thr) ? (uint8_t)0x01 : (uint8_t)0xFF;
                }
            }
        }
        __syncthreads();
        uint8_t* tmp = cur; cur = nxt; nxt = tmp;
    }

    // ---- FC: waves 0,1 (m-tile = wv), one 16-col tile (10 real cols) ----
    if (wv < 2) {
        int4v acc = (int4v){0, 0, 0, 0};
        asm volatile("s_nop 1" ::: );
        const uint8_t* Wl = (const uint8_t*)ws + OFF_FFC;
        const int rr0 = wv * 16 + col;
        #pragma unroll 2
        for (int kt = 0; kt < 16; ++kt) {
            const int k0 = kt * 64 + lg * 16;
            int4v a = *(const int4v*)(cur + rr0 * 1024 + (k0 ^ ((rr0 & 7) << 4)));
            int4v b = *(const int4v*)(Wl + ((size_t)kt << 10) + lane * 16);
            MFMA_I8(acc, a, b);
        }
        asm volatile("s_nop 7\n\ts_nop 7\n\ts_nop 7" ::: );
        if (col < 10) {
            const float sfc = (float)(*(const double*)(ws + OFF_SFC/4));
            const float bb  = bfc[col];
            #pragma unroll
            for (int reg = 0; reg < 4; ++reg) {
                const int rr = wv * 16 + lg * 4 + reg;
                out[(size_t)(row0 + rr) * 10 + col] = (float)acc[reg] * sfc + bb;
            }
        }
    }
}

// ---------------------------------------------------------------------------
// FALLBACK fused (LDS popcount version) — used only if ws too small for v8.
// ---------------------------------------------------------------------------
__global__ __launch_bounds__(512) void bnn_fused_lds(
    const float* __restrict__ x,
    const uint32_t* __restrict__ ws,
    const float* __restrict__ bfc,
    float* __restrict__ out)
{
    __shared__ alignas(16) uint32_t bufA[RWS][32];
    __shared__ alignas(16) uint32_t bufB[RWS][32];
    const int t    = threadIdx.x;
    const int lane = t & 63;
    const int wv   = t >> 6;
    const int row0 = blockIdx.x * RWS;

    #pragma unroll
    for (int rr = 0; rr < 2; ++rr) {
        const int r = wv + 8 * rr;
        const float* xr = x + (size_t)(row0 + r) * 784;
        #pragma unroll
        for (int k = 0; k < 13; ++k) {
            const int idx = k * 64 + lane;
            const bool bit = (idx < 784) && (xr[idx] >= 0.5f);
            unsigned long long m = __ballot(bit);
            if (lane == 0) *(uint64_t*)(&bufA[r][2 * k]) = m;
        }
        if (lane == 0) {
            *(uint64_t*)(&bufA[r][26]) = 0ull;
            *(uint64_t*)(&bufA[r][28]) = 0ull;
            *(uint64_t*)(&bufA[r][30]) = 0ull;
        }
    }
    __syncthreads();

    const uint32_t* Wbase[3] = { ws + OFF_W1/4, ws + OFF_W2/4, ws + OFF_W3/4 };
    const int*      Tbase[3] = { (const int*)(ws + OFF_T1/4), (const int*)(ws + OFF_T2/4), (const int*)(ws + OFF_T3/4) };

    uint32_t (*cur)[32] = bufA;
    uint32_t (*nxt)[32] = bufB;
    const int c0 = t, c1 = t + 512;

    for (int l = 0; l < 3; ++l) {
        uint32_t W0[32], W1[32];
        {
            const uint4* p0 = (const uint4*)(Wbase[l] + (size_t)c0 * 32);
            const uint4* p1 = (const uint4*)(Wbase[l] + (size_t)c1 * 32);
            #pragma unroll
            for (int i = 0; i < 8; ++i) { ((uint4*)W0)[i] = p0[i]; ((uint4*)W1)[i] = p1[i]; }
        }
        const int T0 = Tbase[l][c0];
        const int T1 = Tbase[l][c1];

        for (int r = 0; r < RWS; ++r) {
            uint32_t A[32];
            #pragma unroll
            for (int i = 0; i < 8; ++i) ((uint4*)A)[i] = ((const uint4*)cur[r])[i];
            int pa = 0, pb = 0, pc = 0, pd = 0;
            #pragma unroll
            for (int i = 0; i < 16; ++i) {
                pa += __popc(A[i]      ^ W0[i]);
                pb += __popc(A[i + 16] ^ W0[i + 16]);
                pc += __popc(A[i]      ^ W1[i]);
                pd += __popc(A[i + 16] ^ W1[i + 16]);
            }
            unsigned long long m0 = __ballot((pa + pb) <= T0);
            unsigned long long m1 = __ballot((pc + pd) <= T1);
            if (lane == 0) {
                *(uint64_t*)(&nxt[r][2 * wv])      = m0;
                *(uint64_t*)(&nxt[r][16 + 2 * wv]) = m1;
            }
        }
        __syncthreads();
        uint32_t (*tmp)[32] = cur; cur = nxt; nxt = tmp;
    }

    if (t < RWS * 10) {
        const float sfc = (float)(*(const double*)(ws + OFF_SFC/4));
        const uint32_t* Wfc = ws + OFF_WFC/4;
        const int r = t / 10, ch = t % 10;
        const uint32_t* wrow = Wfc + ch * 32;
        int p = 0;
        #pragma unroll
        for (int i = 0; i < 32; ++i) p += __popc(cur[r][i] ^ wrow[i]);
        out[(size_t)(row0 + r) * 10 + ch] = (float)(1024 - 2 * p) * sfc + bfc[ch];
    }
}

extern "C" void kernel_launch(void* const* d_in, const int* in_sizes, int n_in,
                              void* d_out, int out_size, void* d_ws, size_t ws_size,
                              hipStream_t stream) {
    const float* x   = (const float*)d_in[0];
    const float* w1  = (const float*)d_in[1];
    const float* b1  = (const float*)d_in[2];
    const float* g1  = (const float*)d_in[3];
    const float* be1 = (const float*)d_in[4];
    const float* m1  = (const float*)d_in[5];
    const float* v1  = (const float*)d_in[6];
    const float* w2  = (const float*)d_in[7];
    const float* b2  = (const float*)d_in[8];
    const float* g2  = (const float*)d_in[9];
    const float* be2 = (const float*)d_in[10];
    const float* m2  = (const float*)d_in[11];
    const float* v2  = (const float*)d_in[12];
    const float* w3  = (const float*)d_in[13];
    const float* b3  = (const float*)d_in[14];
    const float* g3  = (const float*)d_in[15];
    const float* be3 = (const float*)d_in[16];
    const float* m3  = (const float*)d_in[17];
    const float* v3  = (const float*)d_in[18];
    const float* wfc = (const float*)d_in[19];
    const float* bfc = (const float*)d_in[20];
    uint32_t* ws = (uint32_t*)d_ws;
    float* out = (float*)d_out;

    // 2 dispatches: prep, then the whole net (MFMA path if ws fits).
    bnn_prep<<<385, 256, 0, stream>>>(
        w1, b1, g1, be1, m1, v1,
        w2, b2, g2, be2, m2, v2,
        w3, b3, g3, be3, m3, v3,
        wfc, ws);

    if (ws_size >= (size_t)WS_NEED_V8) {
        bnn_mfma<<<256, 1024, 0, stream>>>(x, ws, bfc, out);
    } else {
        bnn_fused_lds<<<8192 / RWS, 512, 0, stream>>>(x, ws, bfc, out);
    }
}

// Round 10
// 172.964 us; speedup vs baseline: 1.0561x; 1.0561x over previous
//
#include <hip/hip_runtime.h>
#include <stdint.h>

// Workspace byte offsets
#define OFF_W1  0        // 1024*32 u32 packed sign bits, channel-major (fallback)
#define OFF_W2  131072
#define OFF_W3  262144
#define OFF_WFC 393216   // 10*32 u32 (fallback FC)
#define OFF_T1  395264   // 1024 int32 popcount thresholds (fallback)
#define OFF_T2  399360
#define OFF_T3  403456
#define OFF_SFC 407552   // double: mean|wfc|
// MFMA: fragment-ordered i8 weight files. Layout per layer:
//   frag[(nt*16 + kt)*1024 + lane*16 + e], nt=ch>>4 (64), kt=k>>6 (16),
//   lane = (ch&15) | (((k>>4)&3)<<4), e = k&15.  1 MB per layer.
#define OFF_F1  409600
#define OFF_F2  1458176
#define OFF_F3  2506752
#define OFF_FFC 3555328  // 16 KB: wfc frags (16 cols: 10 real + 6 don't-care)
#define OFF_C1  3571712  // 1024 int32 dot-form thresholds (act = dot >= Cdot)
#define OFF_C2  3575808
#define OFF_C3  3579904
#define WS_NEED_V8 3584000u
#define RWS 16           // rows per block in fallback fused kernel

typedef int int4v __attribute__((ext_vector_type(4)));

// ---------------------------------------------------------------------------
// Prep — one dispatch: W bitpack (fallback) + i8 MFMA frags + thresholds
// (both popcount-form Td and dot-form Cdot) + wfc (both forms). 385 blocks.
// (unchanged from R8 — proven correct)
// ---------------------------------------------------------------------------
__global__ __launch_bounds__(256) void bnn_prep(
    const float* __restrict__ w1, const float* __restrict__ b1, const float* __restrict__ g1,
    const float* __restrict__ be1, const float* __restrict__ m1, const float* __restrict__ v1,
    const float* __restrict__ w2, const float* __restrict__ b2, const float* __restrict__ g2,
    const float* __restrict__ be2, const float* __restrict__ m2, const float* __restrict__ v2,
    const float* __restrict__ w3, const float* __restrict__ b3, const float* __restrict__ g3,
    const float* __restrict__ be3, const float* __restrict__ m3, const float* __restrict__ v3,
    const float* __restrict__ wfc,
    uint32_t* __restrict__ ws)
{
    const int blk  = blockIdx.x;
    const int t    = threadIdx.x;
    const int lane = t & 63;
    const int wv   = t >> 6;

    if (blk < 384) {
        const int gid = blk * 256 + t;      // 0..98303
        const int l   = gid >> 15;          // layer 0..2 (32768 words each)
        const int rem = gid & 32767;
        const int o   = rem >> 5;           // channel
        const int k32 = rem & 31;           // word within channel
        const float *w, *bb, *g, *be, *m, *v;
        int K; uint32_t *Wp, *Fl; int *T, *Cdl;
        if (l == 0)      { w=w1; bb=b1; g=g1; be=be1; m=m1; v=v1; K=784;
                           Wp = ws + OFF_W1/4; Fl = ws + OFF_F1/4;
                           T = (int*)(ws + OFF_T1/4); Cdl = (int*)(ws + OFF_C1/4); }
        else if (l == 1) { w=w2; bb=b2; g=g2; be=be2; m=m2; v=v2; K=1024;
                           Wp = ws + OFF_W2/4; Fl = ws + OFF_F2/4;
                           T = (int*)(ws + OFF_T2/4); Cdl = (int*)(ws + OFF_C2/4); }
        else             { w=w3; bb=b3; g=g3; be=be3; m=m3; v=v3; K=1024;
                           Wp = ws + OFF_W3/4; Fl = ws + OFF_F3/4;
                           T = (int*)(ws + OFF_T3/4); Cdl = (int*)(ws + OFF_C3/4); }

        const int base = 32 * k32;
        uint32_t bits = 0;
        double s = 0.0;
        if (base < K) {
            const float4* p = (const float4*)(w + (size_t)o * K + base);
            const int n4 = (K - base >= 32) ? 8 : 4;   // K=784, k32=24 -> 16 elems
            for (int i = 0; i < n4; ++i) {
                float4 q = p[i];
                bits |= (q.x >= 0.0f) ? (1u << (4*i + 0)) : 0u;
                bits |= (q.y >= 0.0f) ? (1u << (4*i + 1)) : 0u;
                bits |= (q.z >= 0.0f) ? (1u << (4*i + 2)) : 0u;
                bits |= (q.w >= 0.0f) ? (1u << (4*i + 3)) : 0u;
                s += fabs((double)q.x) + fabs((double)q.y)
                   + fabs((double)q.z) + fabs((double)q.w);
            }
        }
        // half-wave (32-lane) xor tree: all lanes of the half get channel sum
        #pragma unroll
        for (int mask = 1; mask <= 16; mask <<= 1)
            s += __shfl_xor(s, mask, 64);
        if (k32 == 0) {
            double scale = s / (double)K;                        // mean|w| > 0
            double r = (double)g[o] / sqrt((double)v[o] + 1e-5); // > 0
            double tt = (((double)m[o] - (double)bb[o]) * r - (double)be[o]) / (scale * r);
            double C  = ceil(tt);                                // act=+1 iff dot >= C
            double Cc = fmax(fmin(C, 100000.0), -100000.0);
            Cdl[o] = (int)Cc;
            double Td = floor(((double)K - C) * 0.5);
            Td = fmax(fmin(Td, 100000.0), -1.0);
            T[o] = (int)Td;
        }
        Wp[(size_t)o * 32 + k32] = bits;                          // bitpacked

        // i8 fragment bytes: 32 bits -> two 16-byte groups in frag order.
        const int nt = o >> 4;
        #pragma unroll
        for (int g2i = 0; g2i < 2; ++g2i) {
            const int kg = base + g2i * 16;
            const int kt = kg >> 6;
            const int lane16 = (o & 15) | (((kg >> 4) & 3) << 4);
            uint32_t fb[4];
            #pragma unroll
            for (int wd = 0; wd < 4; ++wd) {
                uint32_t vv = 0;
                #pragma unroll
                for (int bj = 0; bj < 4; ++bj) {
                    const int idx = g2i*16 + wd*4 + bj;
                    const int kk  = base + idx;
                    uint32_t byte = (kk < K) ? (((bits >> idx) & 1u) ? 0x01u : 0xFFu) : 0x00u;
                    vv |= byte << (8*bj);
                }
                fb[wd] = vv;
            }
            uint32_t* dst = Fl + (size_t)((nt*16 + kt) * 256 + lane16 * 4);
            *(uint4*)dst = *(uint4*)fb;
        }
    } else {
        // wfc: 320 words (10 ch x 32); thread t does word t and (t<64) t+256
        uint32_t* Wp  = ws + OFF_WFC/4;
        uint32_t* Ffc = ws + OFF_FFC/4;
        double s = 0.0;
        #pragma unroll
        for (int part = 0; part < 2; ++part) {
            const int tt_ = t + part * 256;
            if (part == 1 && t >= 64) break;
            const int o = tt_ >> 5, k32 = tt_ & 31;
            const int base = 32 * k32;
            const float4* p = (const float4*)(wfc + o * 1024 + base);
            uint32_t bits = 0;
            #pragma unroll
            for (int i = 0; i < 8; ++i) {
                float4 q = p[i];
                bits |= (q.x >= 0.0f) ? (1u << (4*i + 0)) : 0u;
                bits |= (q.y >= 0.0f) ? (1u << (4*i + 1)) : 0u;
                bits |= (q.z >= 0.0f) ? (1u << (4*i + 2)) : 0u;
                bits |= (q.w >= 0.0f) ? (1u << (4*i + 3)) : 0u;
                s += fabs((double)q.x) + fabs((double)q.y)
                   + fabs((double)q.z) + fabs((double)q.w);
            }
            Wp[tt_] = bits;
            #pragma unroll
            for (int g2i = 0; g2i < 2; ++g2i) {
                const int kg = base + g2i * 16;
                const int kt = kg >> 6;
                const int lane16 = (o & 15) | (((kg >> 4) & 3) << 4);
                uint32_t fb[4];
                #pragma unroll
                for (int wd = 0; wd < 4; ++wd) {
                    uint32_t vv = 0;
                    #pragma unroll
                    for (int bj = 0; bj < 4; ++bj) {
                        const int idx = g2i*16 + wd*4 + bj;
                        vv |= (((bits >> idx) & 1u) ? 0x01u : 0xFFu) << (8*bj);
                    }
                    fb[wd] = vv;
                }
                *(uint4*)(Ffc + (size_t)(kt * 256 + lane16 * 4)) = *(uint4*)fb;
            }
        }
        __shared__ double red[4];
        #pragma unroll
        for (int off = 32; off > 0; off >>= 1) s += __shfl_down(s, off, 64);
        if (lane == 0) red[wv] = s;
        __syncthreads();
        if (t == 0)
            *(double*)(ws + OFF_SFC/4) = (red[0] + red[1] + red[2] + red[3]) / 10240.0;
    }
}

// ---------------------------------------------------------------------------
// v10 (R19): MFMA network via __builtin_amdgcn_mfma_i32_16x16x64_i8.
// R9 post-mortem: inline-asm MFMA + free-floating s_nop guards had NO data
// dependence on the values they protect — plain C++ acc-init (VALU write ->
// srcC) and epilogue reads (MFMA -> VALU read) scheduled into the hazard
// windows under R9's new schedule => absmax 6.5. Fix: use the builtin; the
// compiler knows every MFMA hazard and inserts the wait states itself.
// Structure kept from R9: B register double buffer (kt fully unrolled, kt&1
// static — rule #20 safe), all-1024-thread coalesced x-pack, XOR-swizzled i8
// act buffers in LDS. Fragment layouts identical to R8 (proven by its pass).
// ---------------------------------------------------------------------------
__global__ __launch_bounds__(1024) void bnn_mfma(
    const float* __restrict__ x,
    uint32_t* __restrict__ ws,
    const float* __restrict__ bfc,
    float* __restrict__ out)
{
    __shared__ uint8_t actA[32 * 1024];
    __shared__ uint8_t actB[32 * 1024];
    const int t    = threadIdx.x;
    const int lane = t & 63;
    const int wv   = t >> 6;            // 0..15
    const int row0 = blockIdx.x * 32;

    // ---- stage layer-1 A with ALL threads: i8 sign(2x-1), zero-pad to 1024.
    {
        const int row = t >> 5;           // 0..31
        const float* xr = x + (size_t)(row0 + row) * 784;
        uint8_t* dst = actA + row * 1024;
        #pragma unroll
        for (int wd = 0; wd < 8; ++wd) {
            const int w = (t & 31) + wd * 32;   // u32 word index 0..255
            uint32_t wval = 0;
            if (w < 196) {                       // 196*4 = 784
                const float4 q = *(const float4*)(xr + 4 * w);
                wval  = ((q.x >= 0.5f) ? 0x01u : 0xFFu);
                wval |= ((q.y >= 0.5f) ? 0x01u : 0xFFu) << 8;
                wval |= ((q.z >= 0.5f) ? 0x01u : 0xFFu) << 16;
                wval |= ((q.w >= 0.5f) ? 0x01u : 0xFFu) << 24;
            }
            *(uint32_t*)(dst + ((4 * w) ^ ((row & 7) << 4))) = wval;
        }
    }
    __syncthreads();

    const uint8_t* Wf[3] = { (const uint8_t*)ws + OFF_F1,
                             (const uint8_t*)ws + OFF_F2,
                             (const uint8_t*)ws + OFF_F3 };
    const int* Cd[3] = { (const int*)(ws + OFF_C1/4),
                         (const int*)(ws + OFF_C2/4),
                         (const int*)(ws + OFF_C3/4) };

    uint8_t* cur = actA;
    uint8_t* nxt = actB;
    const int nq  = wv * 4;        // first of this wave's 4 n-tiles
    const int col = lane & 15;
    const int lg  = lane >> 4;     // 0..3

    #pragma unroll 1
    for (int l = 0; l < 3; ++l) {
        int4v acc[2][4];
        #pragma unroll
        for (int m = 0; m < 2; ++m)
            #pragma unroll
            for (int n = 0; n < 4; ++n)
                acc[m][n] = (int4v){0, 0, 0, 0};

        const uint8_t* Wl = Wf[l];
        const int ra = col, rb = 16 + col;

        // B register double buffer; kt loop fully unrolled so kt&1 is static.
        int4v bq[2][4];
        #pragma unroll
        for (int nt = 0; nt < 4; ++nt)
            bq[0][nt] = *(const int4v*)(Wl + ((size_t)((nq + nt) * 16) << 10) + lane * 16);

        #pragma unroll
        for (int kt = 0; kt < 16; ++kt) {
            const int cb = kt & 1, nb = cb ^ 1;
            if (kt < 15) {
                #pragma unroll
                for (int nt = 0; nt < 4; ++nt)
                    bq[nb][nt] = *(const int4v*)(Wl + ((size_t)((nq + nt) * 16 + kt + 1) << 10) + lane * 16);
            }
            const int k0 = kt * 64 + lg * 16;
            int4v a0 = *(const int4v*)(cur + ra * 1024 + (k0 ^ ((ra & 7) << 4)));
            int4v a1 = *(const int4v*)(cur + rb * 1024 + (k0 ^ ((rb & 7) << 4)));
            #pragma unroll
            for (int nt = 0; nt < 4; ++nt) {
                acc[0][nt] = __builtin_amdgcn_mfma_i32_16x16x64_i8(a0, bq[cb][nt], acc[0][nt], 0, 0, 0);
                acc[1][nt] = __builtin_amdgcn_mfma_i32_16x16x64_i8(a1, bq[cb][nt], acc[1][nt], 0, 0, 0);
            }
        }

        const int* Cdl = Cd[l];
        #pragma unroll
        for (int nt = 0; nt < 4; ++nt) {
            const int ch  = (nq + nt) * 16 + col;
            const int thr = Cdl[ch];
            #pragma unroll
            for (int m = 0; m < 2; ++m) {
                #pragma unroll
                for (int reg = 0; reg < 4; ++reg) {
                    const int rr = m * 16 + lg * 4 + reg;
                    nxt[rr * 1024 + (ch ^ ((rr & 7) << 4))] =
                        (acc[m][nt][reg] >= thr) ? (uint8_t)0x01 : (uint8_t)0xFF;
                }
            }
        }
        __syncthreads();
        uint8_t* tmp = cur; cur = nxt; nxt = tmp;
    }

    // ---- FC: waves 0,1 (m-tile = wv), one 16-col tile (10 real cols) ----
    if (wv < 2) {
        int4v acc = (int4v){0, 0, 0, 0};
        const uint8_t* Wl = (const uint8_t*)ws + OFF_FFC;
        const int rr0 = wv * 16 + col;
        #pragma unroll 2
        for (int kt = 0; kt < 16; ++kt) {
            const int k0 = kt * 64 + lg * 16;
            int4v a = *(const int4v*)(cur + rr0 * 1024 + (k0 ^ ((rr0 & 7) << 4)));
            int4v b = *(const int4v*)(Wl + ((size_t)kt << 10) + lane * 16);
            acc = __builtin_amdgcn_mfma_i32_16x16x64_i8(a, b, acc, 0, 0, 0);
        }
        if (col < 10) {
            const float sfc = (float)(*(const double*)(ws + OFF_SFC/4));
            const float bb  = bfc[col];
            #pragma unroll
            for (int reg = 0; reg < 4; ++reg) {
                const int rr = wv * 16 + lg * 4 + reg;
                out[(size_t)(row0 + rr) * 10 + col] = (float)acc[reg] * sfc + bb;
            }
        }
    }
}

// ---------------------------------------------------------------------------
// FALLBACK fused (LDS popcount version) — used only if ws too small.
// ---------------------------------------------------------------------------
__global__ __launch_bounds__(512) void bnn_fused_lds(
    const float* __restrict__ x,
    const uint32_t* __restrict__ ws,
    const float* __restrict__ bfc,
    float* __restrict__ out)
{
    __shared__ alignas(16) uint32_t bufA[RWS][32];
    __shared__ alignas(16) uint32_t bufB[RWS][32];
    const int t    = threadIdx.x;
    const int lane = t & 63;
    const int wv   = t >> 6;
    const int row0 = blockIdx.x * RWS;

    #pragma unroll
    for (int rr = 0; rr < 2; ++rr) {
        const int r = wv + 8 * rr;
        const float* xr = x + (size_t)(row0 + r) * 784;
        #pragma unroll
        for (int k = 0; k < 13; ++k) {
            const int idx = k * 64 + lane;
            const bool bit = (idx < 784) && (xr[idx] >= 0.5f);
            unsigned long long m = __ballot(bit);
            if (lane == 0) *(uint64_t*)(&bufA[r][2 * k]) = m;
        }
        if (lane == 0) {
            *(uint64_t*)(&bufA[r][26]) = 0ull;
            *(uint64_t*)(&bufA[r][28]) = 0ull;
            *(uint64_t*)(&bufA[r][30]) = 0ull;
        }
    }
    __syncthreads();

    const uint32_t* Wbase[3] = { ws + OFF_W1/4, ws + OFF_W2/4, ws + OFF_W3/4 };
    const int*      Tbase[3] = { (const int*)(ws + OFF_T1/4), (const int*)(ws + OFF_T2/4), (const int*)(ws + OFF_T3/4) };

    uint32_t (*cur)[32] = bufA;
    uint32_t (*nxt)[32] = bufB;
    const int c0 = t, c1 = t + 512;

    for (int l = 0; l < 3; ++l) {
        uint32_t W0[32], W1[32];
        {
            const uint4* p0 = (const uint4*)(Wbase[l] + (size_t)c0 * 32);
            const uint4* p1 = (const uint4*)(Wbase[l] + (size_t)c1 * 32);
            #pragma unroll
            for (int i = 0; i < 8; ++i) { ((uint4*)W0)[i] = p0[i]; ((uint4*)W1)[i] = p1[i]; }
        }
        const int T0 = Tbase[l][c0];
        const int T1 = Tbase[l][c1];

        for (int r = 0; r < RWS; ++r) {
            uint32_t A[32];
            #pragma unroll
            for (int i = 0; i < 8; ++i) ((uint4*)A)[i] = ((const uint4*)cur[r])[i];
            int pa = 0, pb = 0, pc = 0, pd = 0;
            #pragma unroll
            for (int i = 0; i < 16; ++i) {
                pa += __popc(A[i]      ^ W0[i]);
                pb += __popc(A[i + 16] ^ W0[i + 16]);
                pc += __popc(A[i]      ^ W1[i]);
                pd += __popc(A[i + 16] ^ W1[i + 16]);
            }
            unsigned long long m0 = __ballot((pa + pb) <= T0);
            unsigned long long m1 = __ballot((pc + pd) <= T1);
            if (lane == 0) {
                *(uint64_t*)(&nxt[r][2 * wv])      = m0;
                *(uint64_t*)(&nxt[r][16 + 2 * wv]) = m1;
            }
        }
        __syncthreads();
        uint32_t (*tmp)[32] = cur; cur = nxt; nxt = tmp;
    }

    if (t < RWS * 10) {
        const float sfc = (float)(*(const double*)(ws + OFF_SFC/4));
        const uint32_t* Wfc = ws + OFF_WFC/4;
        const int r = t / 10, ch = t % 10;
        const uint32_t* wrow = Wfc + ch * 32;
        int p = 0;
        #pragma unroll
        for (int i = 0; i < 32; ++i) p += __popc(cur[r][i] ^ wrow[i]);
        out[(size_t)(row0 + r) * 10 + ch] = (float)(1024 - 2 * p) * sfc + bfc[ch];
    }
}

extern "C" void kernel_launch(void* const* d_in, const int* in_sizes, int n_in,
                              void* d_out, int out_size, void* d_ws, size_t ws_size,
                              hipStream_t stream) {
    const float* x   = (const float*)d_in[0];
    const float* w1  = (const float*)d_in[1];
    const float* b1  = (const float*)d_in[2];
    const float* g1  = (const float*)d_in[3];
    const float* be1 = (const float*)d_in[4];
    const float* m1  = (const float*)d_in[5];
    const float* v1  = (const float*)d_in[6];
    const float* w2  = (const float*)d_in[7];
    const float* b2  = (const float*)d_in[8];
    const float* g2  = (const float*)d_in[9];
    const float* be2 = (const float*)d_in[10];
    const float* m2  = (const float*)d_in[11];
    const float* v2  = (const float*)d_in[12];
    const float* w3  = (const float*)d_in[13];
    const float* b3  = (const float*)d_in[14];
    const float* g3  = (const float*)d_in[15];
    const float* be3 = (const float*)d_in[16];
    const float* m3  = (const float*)d_in[17];
    const float* v3  = (const float*)d_in[18];
    const float* wfc = (const float*)d_in[19];
    const float* bfc = (const float*)d_in[20];
    uint32_t* ws = (uint32_t*)d_ws;
    float* out = (float*)d_out;

    // 2 dispatches: prep, then the whole net (MFMA path if ws fits).
    bnn_prep<<<385, 256, 0, stream>>>(
        w1, b1, g1, be1, m1, v1,
        w2, b2, g2, be2, m2, v2,
        w3, b3, g3, be3, m3, v3,
        wfc, ws);

    if (ws_size >= (size_t)WS_NEED_V8) {
        bnn_mfma<<<256, 1024, 0, stream>>>(x, ws, bfc, out);
    } else {
        bnn_fused_lds<<<8192 / RWS, 512, 0, stream>>>(x, ws, bfc, out);
    }
}